// Round 2
// baseline (636.675 us; speedup 1.0000x reference)
//
#include <hip/hip_runtime.h>
#include <hip/hip_bf16.h>
#include <stdint.h>

typedef __attribute__((ext_vector_type(4))) float f32x4;
typedef __attribute__((ext_vector_type(8))) short bf16x8;

#define LOG2E 1.44269504088896340736f

__device__ __forceinline__ unsigned short f2bf(float f) {
  union { float f; unsigned u; } c; c.f = f;
  unsigned u = c.u + 0x7FFFu + ((c.u >> 16) & 1u);
  return (unsigned short)(u >> 16);
}

__device__ __forceinline__ void gload_lds16(const void* g, void* l) {
  __builtin_amdgcn_global_load_lds((const __attribute__((address_space(1))) void*)g,
                                   (__attribute__((address_space(3))) void*)l, 16, 0, 0);
}

// ---------------- cast x fp32 -> bf16 ----------------
__global__ __launch_bounds__(256) void cast_x_kernel(const float* __restrict__ x,
                                                     unsigned short* __restrict__ o) {
  int i = blockIdx.x * 256 + threadIdx.x;  // 8 elems per thread
  const float4* xv = (const float4*)x;
  float4 a = xv[2 * i], b = xv[2 * i + 1];
  union { uint4 v; unsigned short s[8]; } u;
  u.s[0] = f2bf(a.x); u.s[1] = f2bf(a.y); u.s[2] = f2bf(a.z); u.s[3] = f2bf(a.w);
  u.s[4] = f2bf(b.x); u.s[5] = f2bf(b.y); u.s[6] = f2bf(b.z); u.s[7] = f2bf(b.w);
  ((uint4*)o)[i] = u.v;
}

// ---------------- fold LoRA into per-head weights, output W_eff^T [n][c] bf16 ----------------
// outT row n = h*64 + d (caller offsets per projection); W[h][c][d], A[h][c][r], Bm[h][r][d]
__global__ __launch_bounds__(256) void fold_head_kernel(const float* __restrict__ W,
                                                        const float* __restrict__ A,
                                                        const float* __restrict__ Bm,
                                                        unsigned short* __restrict__ outT,
                                                        float scale) {
  int h = blockIdx.x, cb = blockIdx.y;
  __shared__ unsigned short tile[64 * 65];
  const float* Wh = W + (size_t)h * 65536;
  const float* Ah = A + (size_t)h * 8192;
  const float* Bh = Bm + (size_t)h * 512;
  int t = threadIdx.x;
  for (int i = 0; i < 16; ++i) {
    int idx = i * 256 + t;
    int cl = idx >> 6, d = idx & 63;
    int c = cb * 64 + cl;
    float acc = 0.f;
#pragma unroll
    for (int r = 0; r < 8; ++r) acc += Ah[c * 8 + r] * Bh[r * 64 + d];
    float val = scale * (Wh[c * 64 + d] + 2.0f * acc);
    tile[cl * 65 + d] = f2bf(val);
  }
  __syncthreads();
  for (int i = 0; i < 16; ++i) {
    int idx = i * 256 + t;
    int d = idx >> 6, cl = idx & 63;
    outT[(size_t)(h * 64 + d) * 1024 + cb * 64 + cl] = tile[cl * 65 + d];
  }
}

// ---------------- fold proj LoRA: Wp_eff^T[n][c] = Wp[c][n] + 2*sum_r Ap[c][r]Bp[r][n] ----------------
__global__ __launch_bounds__(256) void fold_proj_kernel(const float* __restrict__ W,
                                                        const float* __restrict__ A,
                                                        const float* __restrict__ Bm,
                                                        unsigned short* __restrict__ outT) {
  int nb = blockIdx.x, cb = blockIdx.y;
  __shared__ unsigned short tile[64 * 65];
  int t = threadIdx.x;
  for (int i = 0; i < 16; ++i) {
    int idx = i * 256 + t;
    int cl = idx >> 6, d = idx & 63;
    int c = cb * 64 + cl, n = nb * 64 + d;
    float acc = 0.f;
#pragma unroll
    for (int r = 0; r < 8; ++r) acc += A[c * 8 + r] * Bm[r * 1024 + n];
    float val = W[(size_t)c * 1024 + n] + 2.0f * acc;
    tile[cl * 65 + d] = f2bf(val);
  }
  __syncthreads();
  for (int i = 0; i < 16; ++i) {
    int idx = i * 256 + t;
    int d = idx >> 6, cl = idx & 63;
    outT[(size_t)(nb * 64 + d) * 1024 + cb * 64 + cl] = tile[cl * 65 + d];
  }
}

// ---------------- GEMM: C[M][N] = A[M][K] * B^T  (B stored [N][K]), bf16 in, fp32 acc ----------------
// MODE 0: bf16 out; MODE 1: fp32 out + bias
template <int MODE>
__global__ __launch_bounds__(256) void gemm_kernel(const unsigned short* __restrict__ A,
                                                   const unsigned short* __restrict__ B,
                                                   void* __restrict__ Cout,
                                                   const float* __restrict__ bias,
                                                   int M, int N, int K) {
  __shared__ unsigned short lds[8192];  // A tile [128][32] then B tile [128][32]
  const int t = threadIdx.x;
  const int m0 = blockIdx.y * 128, n0 = blockIdx.x * 128;
  const int wid = t >> 6, lane = t & 63;
  const int wm = (wid >> 1) * 64, wn = (wid & 1) * 64;
  const int lr = lane & 15, lg = lane >> 4;
  f32x4 acc[4][4];
#pragma unroll
  for (int i = 0; i < 4; ++i)
#pragma unroll
    for (int j = 0; j < 4; ++j) acc[i][j] = (f32x4){0.f, 0.f, 0.f, 0.f};

  for (int k0 = 0; k0 < K; k0 += 32) {
#pragma unroll
    for (int ch = 0; ch < 2; ++ch) {
      int idx = ch * 256 + t;
      int row = idx >> 2, cb = (idx & 3) * 8;  // 4 x 16B chunks per 64B row
      gload_lds16(A + (size_t)(m0 + row) * K + k0 + cb, &lds[idx * 8]);
    }
#pragma unroll
    for (int ch = 0; ch < 2; ++ch) {
      int idx = ch * 256 + t;
      int row = idx >> 2, cb = (idx & 3) * 8;
      gload_lds16(B + (size_t)(n0 + row) * K + k0 + cb, &lds[4096 + idx * 8]);
    }
    __syncthreads();
    bf16x8 af[4], bfr[4];
#pragma unroll
    for (int i = 0; i < 4; ++i) {
      af[i] = *(const bf16x8*)&lds[(wm + i * 16 + lr) * 32 + lg * 8];
      bfr[i] = *(const bf16x8*)&lds[4096 + (wn + i * 16 + lr) * 32 + lg * 8];
    }
#pragma unroll
    for (int i = 0; i < 4; ++i)
#pragma unroll
      for (int j = 0; j < 4; ++j)
        acc[i][j] = __builtin_amdgcn_mfma_f32_16x16x32_bf16(af[i], bfr[j], acc[i][j], 0, 0, 0);
    __syncthreads();
  }

#pragma unroll
  for (int i = 0; i < 4; ++i) {
#pragma unroll
    for (int r = 0; r < 4; ++r) {
      int row = m0 + wm + i * 16 + lg * 4 + r;
#pragma unroll
      for (int j = 0; j < 4; ++j) {
        int col = n0 + wn + j * 16 + lr;
        float v = acc[i][j][r];
        if (MODE == 0)
          ((unsigned short*)Cout)[(size_t)row * N + col] = f2bf(v);
        else
          ((float*)Cout)[(size_t)row * N + col] = v + bias[col];
      }
    }
  }
}

// ---------------- causal flash attention ----------------
// qkv: [B*T][3072] bf16 (q pre-scaled by 1/8), out: [B*T][1024] bf16 (head-concat)
__global__ __launch_bounds__(256) void attn_kernel(const unsigned short* __restrict__ qkv,
                                                   unsigned short* __restrict__ out) {
  __shared__ __align__(16) char kl[8192];  // K tile [64 key][64 d], XOR-swizzled
  __shared__ __align__(16) char vt[8192];  // V^T tile [64 d][64 key], XOR-swizzled
  __shared__ __align__(16) char pl[8192];  // per-wave P [16 q][64 key], XOR-swizzled
  const int t = threadIdx.x;
  const int wid = t >> 6, lane = t & 63;
  const int lr = lane & 15, lg = lane >> 4;
  const int q0 = blockIdx.x * 64;
  const int bh = blockIdx.y;
  const int b = bh >> 4, h = bh & 15;
  const size_t baseRow = (size_t)b * 2048;
  const int q0w = q0 + wid * 16;
  char* pb = pl + wid * 2048;

  bf16x8 qf0, qf1;
  {
    const unsigned short* qp = qkv + (baseRow + q0w + lr) * 3072 + h * 64 + lg * 8;
    qf0 = *(const bf16x8*)qp;
    qf1 = *(const bf16x8*)(qp + 32);
  }

  f32x4 acc_o[4];
#pragma unroll
  for (int i = 0; i < 4; ++i) acc_o[i] = (f32x4){0.f, 0.f, 0.f, 0.f};
  float m_run[4] = {-1e30f, -1e30f, -1e30f, -1e30f};
  float l_run[4] = {0.f, 0.f, 0.f, 0.f};

  const int ktiles = (q0 >> 6) + 1;
  for (int kt = 0; kt < ktiles; ++kt) {
    const int k0 = kt * 64;
    // stage K: reg -> LDS with (row&7)<<4 XOR swizzle (kills 16-way conflict on 128B rows)
#pragma unroll
    for (int ch = 0; ch < 2; ++ch) {
      int idx = ch * 256 + t;
      int kr = idx >> 3, cb = idx & 7;
      uint4 v = *(const uint4*)(qkv + (baseRow + k0 + kr) * 3072 + 1024 + h * 64 + cb * 8);
      *(uint4*)(kl + kr * 128 + ((cb * 16) ^ ((kr & 7) << 4))) = v;
    }
    // stage V transposed: pair keys via shfl_xor(8), packed b32 writes (conflict-free)
#pragma unroll
    for (int ch = 0; ch < 2; ++ch) {
      int idx = ch * 256 + t;
      int kr = idx >> 3, cb = idx & 7;
      union { uint4 v; unsigned w[4]; unsigned short s[8]; } u, p;
      u.v = *(const uint4*)(qkv + (baseRow + k0 + kr) * 3072 + 2048 + h * 64 + cb * 8);
#pragma unroll
      for (int c2 = 0; c2 < 4; ++c2) p.w[c2] = (unsigned)__shfl_xor((int)u.w[c2], 8);
      const int krE2 = (kr & ~1) * 2;
      const bool ev = (kr & 1) == 0;
#pragma unroll
      for (int jj = 0; jj < 4; ++jj) {
        int j = ev ? jj : jj + 4;
        unsigned lo = ev ? u.s[j] : p.s[j];
        unsigned hi = ev ? p.s[j] : u.s[j];
        int d = cb * 8 + j;
        *(unsigned*)(vt + d * 128 + (krE2 ^ (j << 4))) = lo | (hi << 16);
      }
    }
    __syncthreads();

    if (k0 <= q0w + 15) {  // wave-uniform participation
      // S = Q K^T  (16 q x 64 keys)
      f32x4 s[4];
#pragma unroll
      for (int nt = 0; nt < 4; ++nt) {
        int key = nt * 16 + lr;
        const char* kb = kl + key * 128;
        int sw = (key & 7) << 4;
        bf16x8 kf0 = *(const bf16x8*)(kb + ((lg * 16) ^ sw));
        bf16x8 kf1 = *(const bf16x8*)(kb + ((64 + lg * 16) ^ sw));
        f32x4 z = (f32x4){0.f, 0.f, 0.f, 0.f};
        z = __builtin_amdgcn_mfma_f32_16x16x32_bf16(qf0, kf0, z, 0, 0, 0);
        z = __builtin_amdgcn_mfma_f32_16x16x32_bf16(qf1, kf1, z, 0, 0, 0);
        s[nt] = z;
      }
      if (k0 + 63 > q0w) {  // causal mask (only near-diagonal tiles)
#pragma unroll
        for (int nt = 0; nt < 4; ++nt) {
          int key = k0 + nt * 16 + lr;
#pragma unroll
          for (int r = 0; r < 4; ++r)
            if (key > q0w + lg * 4 + r) s[nt][r] = -1e30f;
        }
      }
      // online softmax; row = 16 lanes sharing lg, reduce via shfl_xor 1,2,4,8
#pragma unroll
      for (int r = 0; r < 4; ++r) {
        float mx = fmaxf(fmaxf(s[0][r], s[1][r]), fmaxf(s[2][r], s[3][r]));
        mx = fmaxf(mx, __shfl_xor(mx, 1));
        mx = fmaxf(mx, __shfl_xor(mx, 2));
        mx = fmaxf(mx, __shfl_xor(mx, 4));
        mx = fmaxf(mx, __shfl_xor(mx, 8));
        float mn = fmaxf(m_run[r], mx);
        float sc = exp2f((m_run[r] - mn) * LOG2E);
        m_run[r] = mn;
        float rs = 0.f;
#pragma unroll
        for (int nt = 0; nt < 4; ++nt) {
          float pv = exp2f((s[nt][r] - mn) * LOG2E);
          s[nt][r] = pv;
          rs += pv;
        }
        rs += __shfl_xor(rs, 1);
        rs += __shfl_xor(rs, 2);
        rs += __shfl_xor(rs, 4);
        rs += __shfl_xor(rs, 8);
        l_run[r] = l_run[r] * sc + rs;
#pragma unroll
        for (int dt = 0; dt < 4; ++dt) acc_o[dt][r] *= sc;
      }
      // P -> per-wave LDS (swizzled), then PV
#pragma unroll
      for (int nt = 0; nt < 4; ++nt)
#pragma unroll
        for (int r = 0; r < 4; ++r) {
          int row = lg * 4 + r;
          int key = nt * 16 + lr;
          *(unsigned short*)(pb + row * 128 + ((key * 2) ^ ((row & 7) << 4))) = f2bf(s[nt][r]);
        }
#pragma unroll
      for (int kk = 0; kk < 2; ++kk) {
        bf16x8 pf = *(const bf16x8*)(pb + lr * 128 + ((kk * 64 + lg * 16) ^ ((lr & 7) << 4)));
#pragma unroll
        for (int dt = 0; dt < 4; ++dt) {
          int d = dt * 16 + lr;
          bf16x8 vf = *(const bf16x8*)(vt + d * 128 + ((kk * 64 + lg * 16) ^ ((d & 7) << 4)));
          acc_o[dt] = __builtin_amdgcn_mfma_f32_16x16x32_bf16(pf, vf, acc_o[dt], 0, 0, 0);
        }
      }
    }
    __syncthreads();
  }

#pragma unroll
  for (int r = 0; r < 4; ++r) {
    float inv = 1.0f / l_run[r];
    unsigned short* op = out + (baseRow + q0w + lg * 4 + r) * 1024 + h * 64;
#pragma unroll
    for (int dt = 0; dt < 4; ++dt) op[dt * 16 + lr] = f2bf(acc_o[dt][r] * inv);
  }
}

extern "C" void kernel_launch(void* const* d_in, const int* in_sizes, int n_in,
                              void* d_out, int out_size, void* d_ws, size_t ws_size,
                              hipStream_t stream) {
  const float* x = (const float*)d_in[0];
  const float* Wq = (const float*)d_in[1];
  const float* Wk = (const float*)d_in[2];
  const float* Wv = (const float*)d_in[3];
  const float* Aq = (const float*)d_in[4];
  const float* Bq = (const float*)d_in[5];
  const float* Ak = (const float*)d_in[6];
  const float* Bk = (const float*)d_in[7];
  const float* Av = (const float*)d_in[8];
  const float* Bv = (const float*)d_in[9];
  const float* Wp = (const float*)d_in[10];
  const float* bp = (const float*)d_in[11];
  const float* Ap = (const float*)d_in[12];
  const float* Bp = (const float*)d_in[13];

  // workspace carve (bf16 elems):
  //   xb   16.8MB  (x cast; REUSED as attention output after QKV GEMM)
  //   weff  6.3MB  (Wq/Wk/Wv effective, transposed, bf16)
  //   wpeff 2.1MB  (Wp effective, transposed, bf16)
  //   qkvb 50.3MB  (QKV activations)
  // peak ~75MB
  unsigned short* xb = (unsigned short*)d_ws;
  unsigned short* weff = xb + 8388608;
  unsigned short* wpeff = weff + 3145728;
  unsigned short* qkvb = wpeff + 1048576;
  unsigned short* attb = xb;  // alias: x dead after QKV GEMM

  cast_x_kernel<<<4096, 256, 0, stream>>>(x, xb);
  dim3 fg(16, 16);
  fold_head_kernel<<<fg, 256, 0, stream>>>(Wq, Aq, Bq, weff, 0.125f);            // softmax scale folded
  fold_head_kernel<<<fg, 256, 0, stream>>>(Wk, Ak, Bk, weff + 1048576, 1.0f);
  fold_head_kernel<<<fg, 256, 0, stream>>>(Wv, Av, Bv, weff + 2097152, 1.0f);
  fold_proj_kernel<<<fg, 256, 0, stream>>>(Wp, Ap, Bp, wpeff);

  gemm_kernel<0><<<dim3(24, 64), 256, 0, stream>>>(xb, weff, (void*)qkvb, nullptr, 8192, 3072, 1024);
  attn_kernel<<<dim3(32, 64), 256, 0, stream>>>(qkvb, attb);
  gemm_kernel<1><<<dim3(8, 64), 256, 0, stream>>>(attb, wpeff, d_out, bp, 8192, 1024, 1024);
}

// Round 4
// 564.683 us; speedup vs baseline: 1.1275x; 1.1275x over previous
//
#include <hip/hip_runtime.h>
#include <hip/hip_bf16.h>
#include <stdint.h>

typedef __attribute__((ext_vector_type(4))) float f32x4;
typedef __attribute__((ext_vector_type(8))) short bf16x8;

#define LOG2E 1.44269504088896340736f

__device__ __forceinline__ unsigned short f2bf(float f) {
  union { float f; unsigned u; } c; c.f = f;
  unsigned u = c.u + 0x7FFFu + ((c.u >> 16) & 1u);
  return (unsigned short)(u >> 16);
}

__device__ __forceinline__ void gload_lds16(const void* g, void* l) {
  __builtin_amdgcn_global_load_lds((const __attribute__((address_space(1))) void*)g,
                                   (__attribute__((address_space(3))) void*)l, 16, 0, 0);
}

// ---------------- cast x fp32 -> bf16 ----------------
__global__ __launch_bounds__(256) void cast_x_kernel(const float* __restrict__ x,
                                                     unsigned short* __restrict__ o) {
  int i = blockIdx.x * 256 + threadIdx.x;  // 8 elems per thread
  const float4* xv = (const float4*)x;
  float4 a = xv[2 * i], b = xv[2 * i + 1];
  union { uint4 v; unsigned short s[8]; } u;
  u.s[0] = f2bf(a.x); u.s[1] = f2bf(a.y); u.s[2] = f2bf(a.z); u.s[3] = f2bf(a.w);
  u.s[4] = f2bf(b.x); u.s[5] = f2bf(b.y); u.s[6] = f2bf(b.z); u.s[7] = f2bf(b.w);
  ((uint4*)o)[i] = u.v;
}

// ---------------- fold LoRA into per-head weights, output W_eff^T [n][c] bf16 ----------------
__global__ __launch_bounds__(256) void fold_head_kernel(const float* __restrict__ W,
                                                        const float* __restrict__ A,
                                                        const float* __restrict__ Bm,
                                                        unsigned short* __restrict__ outT,
                                                        float scale) {
  int h = blockIdx.x, cb = blockIdx.y;
  __shared__ unsigned short tile[64 * 65];
  const float* Wh = W + (size_t)h * 65536;
  const float* Ah = A + (size_t)h * 8192;
  const float* Bh = Bm + (size_t)h * 512;
  int t = threadIdx.x;
  for (int i = 0; i < 16; ++i) {
    int idx = i * 256 + t;
    int cl = idx >> 6, d = idx & 63;
    int c = cb * 64 + cl;
    float acc = 0.f;
#pragma unroll
    for (int r = 0; r < 8; ++r) acc += Ah[c * 8 + r] * Bh[r * 64 + d];
    float val = scale * (Wh[c * 64 + d] + 2.0f * acc);
    tile[cl * 65 + d] = f2bf(val);
  }
  __syncthreads();
  for (int i = 0; i < 16; ++i) {
    int idx = i * 256 + t;
    int d = idx >> 6, cl = idx & 63;
    outT[(size_t)(h * 64 + d) * 1024 + cb * 64 + cl] = tile[cl * 65 + d];
  }
}

// ---------------- fold proj LoRA ----------------
__global__ __launch_bounds__(256) void fold_proj_kernel(const float* __restrict__ W,
                                                        const float* __restrict__ A,
                                                        const float* __restrict__ Bm,
                                                        unsigned short* __restrict__ outT) {
  int nb = blockIdx.x, cb = blockIdx.y;
  __shared__ unsigned short tile[64 * 65];
  int t = threadIdx.x;
  for (int i = 0; i < 16; ++i) {
    int idx = i * 256 + t;
    int cl = idx >> 6, d = idx & 63;
    int c = cb * 64 + cl, n = nb * 64 + d;
    float acc = 0.f;
#pragma unroll
    for (int r = 0; r < 8; ++r) acc += A[c * 8 + r] * Bm[r * 1024 + n];
    float val = W[(size_t)c * 1024 + n] + 2.0f * acc;
    tile[cl * 65 + d] = f2bf(val);
  }
  __syncthreads();
  for (int i = 0; i < 16; ++i) {
    int idx = i * 256 + t;
    int d = idx >> 6, cl = idx & 63;
    outT[(size_t)(nb * 64 + d) * 1024 + cb * 64 + cl] = tile[cl * 65 + d];
  }
}

// ---------------- GEMM: C[M][N] = A[M][K] * B^T (B stored [N][K]), bf16 in, fp32 acc ----------------
template <int MODE>
__global__ __launch_bounds__(256) void gemm_kernel(const unsigned short* __restrict__ A,
                                                   const unsigned short* __restrict__ B,
                                                   void* __restrict__ Cout,
                                                   const float* __restrict__ bias,
                                                   int M, int N, int K) {
  __shared__ unsigned short lds[8192];
  const int t = threadIdx.x;
  const int m0 = blockIdx.y * 128, n0 = blockIdx.x * 128;
  const int wid = t >> 6, lane = t & 63;
  const int wm = (wid >> 1) * 64, wn = (wid & 1) * 64;
  const int lr = lane & 15, lg = lane >> 4;
  f32x4 acc[4][4];
#pragma unroll
  for (int i = 0; i < 4; ++i)
#pragma unroll
    for (int j = 0; j < 4; ++j) acc[i][j] = (f32x4){0.f, 0.f, 0.f, 0.f};

  for (int k0 = 0; k0 < K; k0 += 32) {
#pragma unroll
    for (int ch = 0; ch < 2; ++ch) {
      int idx = ch * 256 + t;
      int row = idx >> 2, cb = (idx & 3) * 8;
      gload_lds16(A + (size_t)(m0 + row) * K + k0 + cb, &lds[idx * 8]);
    }
#pragma unroll
    for (int ch = 0; ch < 2; ++ch) {
      int idx = ch * 256 + t;
      int row = idx >> 2, cb = (idx & 3) * 8;
      gload_lds16(B + (size_t)(n0 + row) * K + k0 + cb, &lds[4096 + idx * 8]);
    }
    __syncthreads();
    bf16x8 af[4], bfr[4];
#pragma unroll
    for (int i = 0; i < 4; ++i) {
      af[i] = *(const bf16x8*)&lds[(wm + i * 16 + lr) * 32 + lg * 8];
      bfr[i] = *(const bf16x8*)&lds[4096 + (wn + i * 16 + lr) * 32 + lg * 8];
    }
#pragma unroll
    for (int i = 0; i < 4; ++i)
#pragma unroll
      for (int j = 0; j < 4; ++j)
        acc[i][j] = __builtin_amdgcn_mfma_f32_16x16x32_bf16(af[i], bfr[j], acc[i][j], 0, 0, 0);
    __syncthreads();
  }

#pragma unroll
  for (int i = 0; i < 4; ++i) {
#pragma unroll
    for (int r = 0; r < 4; ++r) {
      int row = m0 + wm + i * 16 + lg * 4 + r;
#pragma unroll
      for (int j = 0; j < 4; ++j) {
        int col = n0 + wn + j * 16 + lr;
        float v = acc[i][j][r];
        if (MODE == 0)
          ((unsigned short*)Cout)[(size_t)row * N + col] = f2bf(v);
        else
          ((float*)Cout)[(size_t)row * N + col] = v + bias[col];
      }
    }
  }
}

// ---------------- causal flash attention (balanced, double-buffered, M=0 softmax) ----------------
// qkv: [B*T][3072] bf16, q pre-scaled by 0.125*log2(e)  ->  P = exp2(S)
// out: [B*T][1024] bf16 (head-concat)
// block = (j, bh): processes q-tile 31-j then q-tile j  => 33 k-tile iterations for every block
__global__ __launch_bounds__(256) void attn_kernel(const unsigned short* __restrict__ qkv,
                                                   unsigned short* __restrict__ out) {
  __shared__ __align__(16) char kl[2][8192];  // K tile [64 key][64 d], swz (k&7)<<4
  __shared__ __align__(16) char vt[2][8192];  // V^T tile [64 d][64 key], swz ((d&7)^((d>>3)&7))<<4
  __shared__ __align__(16) char pl[8192];     // per-wave P [16 q][64 key], swz ((q&1)<<4)|((q&12)<<3)
  const int t = threadIdx.x;
  const int wid = t >> 6, lane = t & 63;
  const int lr = lane & 15, lg = lane >> 4;
  const int jb = blockIdx.x;  // 0..15
  const int bh = blockIdx.y;
  const int b = bh >> 4, h = bh & 15;
  const size_t baseRow = (size_t)b * 2048;
  char* pb = pl + wid * 2048;
  const int s_kr = t >> 3;  // 0..31 staging row (ch adds 32)
  const int s_cb = t & 7;   // 16B chunk

#pragma unroll 1
  for (int ph = 0; ph < 2; ++ph) {
    const int qtile = ph ? jb : 31 - jb;
    const int nkt = qtile + 1;
    const int q0w = qtile * 64 + wid * 16;

    const unsigned short* qp = qkv + (baseRow + q0w + lr) * 3072 + h * 64 + lg * 8;
    bf16x8 qf0 = *(const bf16x8*)qp;
    bf16x8 qf1 = *(const bf16x8*)(qp + 32);

    f32x4 acc_o[4];
#pragma unroll
    for (int i = 0; i < 4; ++i) acc_o[i] = (f32x4){0.f, 0.f, 0.f, 0.f};
    float l_part[4] = {0.f, 0.f, 0.f, 0.f};

    auto loadKV = [&](int kt, uint4* kreg, uint4* vreg) {
      const unsigned short* base = qkv + (baseRow + kt * 64) * 3072 + h * 64 + s_cb * 8;
      kreg[0] = *(const uint4*)(base + 1024 + (size_t)s_kr * 3072);
      kreg[1] = *(const uint4*)(base + 1024 + (size_t)(s_kr + 32) * 3072);
      vreg[0] = *(const uint4*)(base + 2048 + (size_t)s_kr * 3072);
      vreg[1] = *(const uint4*)(base + 2048 + (size_t)(s_kr + 32) * 3072);
    };
    auto storeKV = [&](int buf, uint4* kreg, uint4* vreg) {
#pragma unroll
      for (int ch = 0; ch < 2; ++ch) {
        int kr = ch * 32 + s_kr;
        *(uint4*)(kl[buf] + kr * 128 + ((s_cb * 16) ^ ((kr & 7) << 4))) = kreg[ch];
      }
#pragma unroll
      for (int ch = 0; ch < 2; ++ch) {
        int kr = ch * 32 + s_kr;
        union { uint4 v; unsigned w[4]; unsigned short s[8]; } u, p;
        u.v = vreg[ch];
#pragma unroll
        for (int c2 = 0; c2 < 4; ++c2) p.w[c2] = (unsigned)__shfl_xor((int)u.w[c2], 8);
        const int krE2 = (kr & ~1) * 2;
        const bool ev = (kr & 1) == 0;
#pragma unroll
        for (int jj = 0; jj < 4; ++jj) {
          int j = ev ? jj : jj + 4;
          unsigned lo = ev ? u.s[j] : p.s[j];
          unsigned hi = ev ? p.s[j] : u.s[j];
          int d = s_cb * 8 + j;
          int sw = (((d & 7) ^ ((d >> 3) & 7)) << 4);
          *(unsigned*)(vt[buf] + d * 128 + (krE2 ^ sw)) = lo | (hi << 16);
        }
      }
    };

    {  // prologue: stage tile 0 into buf 0
      uint4 kreg[2], vreg[2];
      loadKV(0, kreg, vreg);
      storeKV(0, kreg, vreg);
    }
    __syncthreads();

#pragma unroll 1
    for (int kt = 0; kt < nkt; ++kt) {
      const int cur = kt & 1;
      uint4 kreg2[2], vreg2[2];
      const bool pf = (kt + 1 < nkt);
      if (pf) loadKV(kt + 1, kreg2, vreg2);  // issue early (T14)

      // ---- S = Q K^T on buf[cur] ----
      const char* klc = kl[cur];
      f32x4 s[4];
#pragma unroll
      for (int nt = 0; nt < 4; ++nt) {
        int key = nt * 16 + lr;
        const char* kb = klc + key * 128;
        int sw = (key & 7) << 4;
        bf16x8 kf0 = *(const bf16x8*)(kb + ((lg * 16) ^ sw));
        bf16x8 kf1 = *(const bf16x8*)(kb + ((64 + lg * 16) ^ sw));
        f32x4 z = (f32x4){0.f, 0.f, 0.f, 0.f};
        z = __builtin_amdgcn_mfma_f32_16x16x32_bf16(qf0, kf0, z, 0, 0, 0);
        z = __builtin_amdgcn_mfma_f32_16x16x32_bf16(qf1, kf1, z, 0, 0, 0);
        s[nt] = z;
      }
      if (kt == qtile) {  // causal mask on diagonal tile
#pragma unroll
        for (int nt = 0; nt < 4; ++nt) {
          int key = kt * 64 + nt * 16 + lr;
#pragma unroll
          for (int r = 0; r < 4; ++r)
            if (key > q0w + lg * 4 + r) s[nt][r] = -1e30f;
        }
      }
      // ---- P = exp2(S) (M=0, no reductions); accumulate per-lane l ----
#pragma unroll
      for (int nt = 0; nt < 4; ++nt)
#pragma unroll
        for (int r = 0; r < 4; ++r) {
          float pv = exp2f(s[nt][r]);
          s[nt][r] = pv;
          l_part[r] += pv;
        }
      // ---- P -> per-wave LDS (conflict-free swizzle) ----
#pragma unroll
      for (int nt = 0; nt < 4; ++nt)
#pragma unroll
        for (int r = 0; r < 4; ++r) {
          int row = lg * 4 + r;
          int key = nt * 16 + lr;
          int sw = ((row & 1) << 4) | ((row & 12) << 3);
          *(unsigned short*)(pb + row * 128 + ((key * 2) ^ sw)) = f2bf(s[nt][r]);
        }
      // ---- O += P V ----
#pragma unroll
      for (int kk = 0; kk < 2; ++kk) {
        int swp = ((lr & 1) << 4) | ((lr & 12) << 3);
        bf16x8 pf = *(const bf16x8*)(pb + lr * 128 + ((kk * 64 + lg * 16) ^ swp));
#pragma unroll
        for (int dt = 0; dt < 4; ++dt) {
          int d = dt * 16 + lr;
          int swv = (((d & 7) ^ ((d >> 3) & 7)) << 4);
          bf16x8 vf = *(const bf16x8*)(vt[cur] + d * 128 + ((kk * 64 + lg * 16) ^ swv));
          acc_o[dt] = __builtin_amdgcn_mfma_f32_16x16x32_bf16(pf, vf, acc_o[dt], 0, 0, 0);
        }
      }

      if (pf) storeKV(cur ^ 1, kreg2, vreg2);  // write late (T14)
      __syncthreads();
    }

    // ---- epilogue: one sum-reduce, normalize, store ----
#pragma unroll
    for (int r = 0; r < 4; ++r) {
      float v = l_part[r];
      v += __shfl_xor(v, 1);
      v += __shfl_xor(v, 2);
      v += __shfl_xor(v, 4);
      v += __shfl_xor(v, 8);
      l_part[r] = v;
    }
#pragma unroll
    for (int r = 0; r < 4; ++r) {
      float inv = 1.0f / l_part[r];
      unsigned short* op = out + (baseRow + q0w + lg * 4 + r) * 1024 + h * 64;
#pragma unroll
      for (int dt = 0; dt < 4; ++dt) op[dt * 16 + lr] = f2bf(acc_o[dt][r] * inv);
    }
  }
}

extern "C" void kernel_launch(void* const* d_in, const int* in_sizes, int n_in,
                              void* d_out, int out_size, void* d_ws, size_t ws_size,
                              hipStream_t stream) {
  const float* x = (const float*)d_in[0];
  const float* Wq = (const float*)d_in[1];
  const float* Wk = (const float*)d_in[2];
  const float* Wv = (const float*)d_in[3];
  const float* Aq = (const float*)d_in[4];
  const float* Bq = (const float*)d_in[5];
  const float* Ak = (const float*)d_in[6];
  const float* Bk = (const float*)d_in[7];
  const float* Av = (const float*)d_in[8];
  const float* Bv = (const float*)d_in[9];
  const float* Wp = (const float*)d_in[10];
  const float* bp = (const float*)d_in[11];
  const float* Ap = (const float*)d_in[12];
  const float* Bp = (const float*)d_in[13];

  unsigned short* xb = (unsigned short*)d_ws;
  unsigned short* weff = xb + 8388608;
  unsigned short* wpeff = weff + 3145728;
  unsigned short* qkvb = wpeff + 1048576;
  unsigned short* attb = xb;  // alias: x dead after QKV GEMM

  cast_x_kernel<<<4096, 256, 0, stream>>>(x, xb);
  dim3 fg(16, 16);
  // q scale = softmax 1/8, with log2(e) folded so attention uses exp2 directly
  fold_head_kernel<<<fg, 256, 0, stream>>>(Wq, Aq, Bq, weff, 0.125f * LOG2E);
  fold_head_kernel<<<fg, 256, 0, stream>>>(Wk, Ak, Bk, weff + 1048576, 1.0f);
  fold_head_kernel<<<fg, 256, 0, stream>>>(Wv, Av, Bv, weff + 2097152, 1.0f);
  fold_proj_kernel<<<fg, 256, 0, stream>>>(Wp, Ap, Bp, wpeff);

  gemm_kernel<0><<<dim3(24, 64), 256, 0, stream>>>(xb, weff, (void*)qkvb, nullptr, 8192, 3072, 1024);
  attn_kernel<<<dim3(16, 64), 256, 0, stream>>>(qkvb, attb);
  gemm_kernel<1><<<dim3(8, 64), 256, 0, stream>>>(attb, wpeff, d_out, bp, 8192, 1024, 1024);
}